// Round 4
// baseline (1153.109 us; speedup 1.0000x reference)
//
#include <hip/hip_runtime.h>

#define T_STEPS 512
#define NTRAJ   4096
#define LAT     32
#define INPD    16
#define HID     20
#define CAT     48

__device__ __forceinline__ float fast_tanh(float x) {
    float e = __expf(2.0f * x);
    float r = __builtin_amdgcn_rcpf(e + 1.0f);
    return fmaf(-2.0f, r, 1.0f);
}
__device__ __forceinline__ float fast_sigmoid(float x) {
    float e = __expf(-x);
    return __builtin_amdgcn_rcpf(e + 1.0f);
}

// acc += ror16<I>(ring) * w, as ONE VALU instruction (DPP folded into fmac).
// row_ror:I — lane reads lane (l-I)&15 within its 16-lane row (same semantics
// the R3 weight tables were built and verified against).
#define FMAC_DPP(acc, ring, w, I) \
    asm("v_fmac_f32_dpp %0, %1, %2 row_ror:" #I " row_mask:0xf bank_mask:0xf" \
        : "+v"(acc) : "v"(ring), "v"(w))

#define REP15(M) M(1) M(2) M(3) M(4) M(5) M(6) M(7) M(8) \
                 M(9) M(10) M(11) M(12) M(13) M(14) M(15)

// One wave = one trajectory. Systolic DPP-ring matvecs, 1 instr/MAC.
// Lane layout: c = lane&31 (column), g = lane>>5 (0=u, 1=r gate),
// p = (lane>>4)&1 (row parity -> which 16-wide slot block this row holds).
__global__ __launch_bounds__(256, 2) void rnn_fused(
    const float* __restrict__ data,
    const float* __restrict__ Wu1, const float* __restrict__ bu1,
    const float* __restrict__ Wu2, const float* __restrict__ bu2,
    const float* __restrict__ Wr1, const float* __restrict__ br1,
    const float* __restrict__ Wr2, const float* __restrict__ br2,
    const float* __restrict__ Wn1, const float* __restrict__ bn1,
    const float* __restrict__ Wn2, const float* __restrict__ bn2,
    float* __restrict__ out_yi, float* __restrict__ out_lat)
{
    const int tid  = threadIdx.x;
    const int w    = tid >> 6;
    const int lane = tid & 63;
    const int c    = lane & 31;
    const int g    = lane >> 5;
    const int p    = (lane >> 4) & 1;
    const int b    = (blockIdx.x << 2) + w;

    const float* W1 = g ? Wr1 : Wu1;
    const float* B1 = g ? br1 : bu1;
    const float* W2 = g ? Wr2 : Wu2;
    const float* B2 = g ? br2 : bu2;
    const bool realc = (c < HID);

    // Stationary per-lane weights, indexed by rotation step i.
    //   nat ring  -> slot sa = 16*p     + ((c-i)&15)
    //   swap ring -> slot sb = 16*(1-p) + ((c-i)&15)
    //   x ring    -> slot sx = 32       + ((c-i)&15)
    float wa_a[16], wa_b[16], wa_x[16], wb_a[16], wb_b[16];
    float wc_a[16], wc_b[16], wc_x[16], wd_a[16], wd_b[16];
    #pragma unroll
    for (int i = 0; i < 16; ++i) {
        int s  = (c - i) & 15;
        int sa = 16 * p + s;
        int sb = 16 * (1 - p) + s;
        int sx = 32 + s;
        wa_a[i] = realc ? W1[sa * HID + c] : 0.0f;
        wa_b[i] = realc ? W1[sb * HID + c] : 0.0f;
        wa_x[i] = realc ? W1[sx * HID + c] : 0.0f;
        wb_a[i] = (sa < HID) ? W2[sa * LAT + c] : 0.0f;
        wb_b[i] = (sb < HID) ? W2[sb * LAT + c] : 0.0f;
        wc_a[i] = realc ? Wn1[sa * HID + c] : 0.0f;
        wc_b[i] = realc ? Wn1[sb * HID + c] : 0.0f;
        wc_x[i] = realc ? Wn1[sx * HID + c] : 0.0f;
        wd_a[i] = (sa < HID) ? Wn2[sa * LAT + c] : 0.0f;
        wd_b[i] = (sb < HID) ? Wn2[sb * LAT + c] : 0.0f;
    }
    const float ba = realc ? B1[c] : 0.0f;
    const float bb = B2[c];
    const float bc = realc ? bn1[c] : 0.0f;
    const float bd = bn2[c];

    // x ring: lane l holds x[l&15]; 2-step prefetch pipeline.
    const float* xptr = data + (size_t)b * T_STEPS * INPD + (lane & 15);
    float x0 = xptr[0];
    float x1 = xptr[INPD];

    float y  = 0.0f;   // y[c], maintained on ALL 64 lanes
    float y2 = 0.0f;   // y[c^16]
    float* olat = out_lat + (size_t)b * T_STEPS * LAT + c;

    for (int t = 0; t < T_STEPS; ++t) {
        int tf = t + 2; tf = (tf < T_STEPS) ? tf : (T_STEPS - 1);
        float xn = xptr[(size_t)tf * INPD];

        // ---- Phase A: layer-1 of own gate, K=48 = y(32) + x(16) ----
        float acc[4] = {ba, 0.f, 0.f, 0.f};
        acc[0] = fmaf(y,  wa_a[0], acc[0]);
        acc[1] = fmaf(y2, wa_b[0], acc[1]);
        acc[2] = fmaf(x0, wa_x[0], acc[2]);
        #define PA(i) \
            FMAC_DPP(acc[(i)&3],     y,  wa_a[(i)], i); \
            FMAC_DPP(acc[((i)+1)&3], y2, wa_b[(i)], i); \
            FMAC_DPP(acc[((i)+2)&3], x0, wa_x[(i)], i);
        REP15(PA)
        #undef PA
        float h1 = fast_tanh((acc[0] + acc[1]) + (acc[2] + acc[3]));
        float h2 = __shfl_xor(h1, 16);

        // ---- Phase B: layer-2 of own gate, K=20 (zero-padded to 32) ----
        float bcc[4] = {bb, 0.f, 0.f, 0.f};
        bcc[0] = fmaf(h1, wb_a[0], bcc[0]);
        bcc[1] = fmaf(h2, wb_b[0], bcc[1]);
        #define PB(i) \
            FMAC_DPP(bcc[(i)&3],     h1, wb_a[(i)], i); \
            FMAC_DPP(bcc[((i)+1)&3], h2, wb_b[(i)], i);
        REP15(PB)
        #undef PB
        float gate = fast_sigmoid((bcc[0] + bcc[1]) + (bcc[2] + bcc[3]));

        float exch  = __shfl_xor(gate, 32);   // other gate's value for col c
        float u_all = g ? exch : gate;
        float r_all = g ? gate : exch;
        float ry    = r_all * y;              // cc slot c, all lanes
        float ry2   = __shfl_xor(ry, 16);

        // ---- Phase C: layer-1 of n, K=48 = ry(32) + x(16), both halves ----
        float ccc[4] = {bc, 0.f, 0.f, 0.f};
        ccc[0] = fmaf(ry,  wc_a[0], ccc[0]);
        ccc[1] = fmaf(ry2, wc_b[0], ccc[1]);
        ccc[2] = fmaf(x0,  wc_x[0], ccc[2]);
        #define PC(i) \
            FMAC_DPP(ccc[(i)&3],     ry,  wc_a[(i)], i); \
            FMAC_DPP(ccc[((i)+1)&3], ry2, wc_b[(i)], i); \
            FMAC_DPP(ccc[((i)+2)&3], x0,  wc_x[(i)], i);
        REP15(PC)
        #undef PC
        float hn  = fast_tanh((ccc[0] + ccc[1]) + (ccc[2] + ccc[3]));
        float hn2 = __shfl_xor(hn, 16);

        // ---- Phase D: layer-2 of n, K=20 (zero-padded to 32) ----
        float dcc[4] = {bd, 0.f, 0.f, 0.f};
        dcc[0] = fmaf(hn,  wd_a[0], dcc[0]);
        dcc[1] = fmaf(hn2, wd_b[0], dcc[1]);
        #define PD(i) \
            FMAC_DPP(dcc[(i)&3],     hn,  wd_a[(i)], i); \
            FMAC_DPP(dcc[((i)+1)&3], hn2, wd_b[(i)], i);
        REP15(PD)
        #undef PD
        float n = fast_tanh((dcc[0] + dcc[1]) + (dcc[2] + dcc[3]));

        // ---- y' = (1-u)*n + u*y, maintained on all lanes ----
        float ny = fmaf(u_all, y - n, n);
        y  = ny;
        y2 = __shfl_xor(ny, 16);
        if (lane < 32) olat[(size_t)t * LAT] = ny;

        x0 = x1; x1 = xn;
    }

    if (lane < 32) out_yi[(size_t)b * LAT + c] = y;
}

extern "C" void kernel_launch(void* const* d_in, const int* in_sizes, int n_in,
                              void* d_out, int out_size, void* d_ws, size_t ws_size,
                              hipStream_t stream) {
    const float* data = (const float*)d_in[0];
    const float* Wu1 = (const float*)d_in[2];
    const float* bu1 = (const float*)d_in[3];
    const float* Wu2 = (const float*)d_in[4];
    const float* bu2 = (const float*)d_in[5];
    const float* Wr1 = (const float*)d_in[6];
    const float* br1 = (const float*)d_in[7];
    const float* Wr2 = (const float*)d_in[8];
    const float* br2 = (const float*)d_in[9];
    const float* Wn1 = (const float*)d_in[10];
    const float* bn1 = (const float*)d_in[11];
    const float* Wn2 = (const float*)d_in[12];
    const float* bn2 = (const float*)d_in[13];

    float* out_yi  = (float*)d_out;
    float* out_lat = out_yi + (size_t)NTRAJ * LAT;

    rnn_fused<<<NTRAJ / 4, 256, 0, stream>>>(
        data, Wu1, bu1, Wu2, bu2, Wr1, br1, Wr2, br2, Wn1, bn1, Wn2, bn2,
        out_yi, out_lat);
}